// Round 5
// baseline (135.529 us; speedup 1.0000x reference)
//
#include <hip/hip_runtime.h>

// Problem constants
#define BB   8
#define CC   256
#define HH   64
#define WW   64
#define CR   64     // reduced channels
#define NG   32     // groups
#define GC   8      // group_channels
#define KK   25     // 5x5 taps
#define HW   (HH*WW)

typedef __attribute__((ext_vector_type(8))) short short8;   // 8 bf16 = 4 VGPRs
typedef __attribute__((ext_vector_type(4))) float f32x4;    // MFMA C/D

__device__ __forceinline__ unsigned short f2bf(float f) {
    unsigned u = __builtin_bit_cast(unsigned, f);
    u += 0x7FFFu + ((u >> 16) & 1u);          // round-to-nearest-even
    return (unsigned short)(u >> 16);
}

// ---------------------------------------------------------------------------
// prep (fused): blocks [0,256) pack w2 -> bf16 B-frag layout (w2p);
// blocks [256,320) fold BN into w1 -> bf16 A-frag layout (w1a) + b1f.
// ---------------------------------------------------------------------------
__global__ __launch_bounds__(256) void prep_kernel(
    const float* __restrict__ w1, const float* __restrict__ b1,
    const float* __restrict__ gamma, const float* __restrict__ beta,
    const float* __restrict__ mean, const float* __restrict__ var,
    const float* __restrict__ w2,
    unsigned short* __restrict__ w1a, float* __restrict__ b1f,
    unsigned short* __restrict__ w2p)
{
    int gid = blockIdx.x;
    if (gid < 256) {
        // ---- w2 pack: B[k][n]=w2[g*25+nl][k]; lane l: n=l&15, k=ki*32+(l>>4)*8+j
        int idx = gid * 256 + threadIdx.x;   // 0..65535
        int j  = idx & 7;
        int l  = (idx >> 3) & 63;
        int ki = (idx >> 9) & 1;
        int nt = (idx >> 10) & 1;
        int g  = idx >> 11;
        int nl = nt * 16 + (l & 15);
        int k  = ki * 32 + (l >> 4) * 8 + j;
        float v = (nl < KK) ? w2[(g * KK + nl) * CR + k] : 0.0f;
        w2p[idx] = f2bf(v);
    } else {
        // ---- w1 fold+pack: A[m=r][k=c]; lane l: r=mt*16+(l&15), c=ki*32+(l>>4)*8+j
        int idx = (gid - 256) * 256 + threadIdx.x;   // 0..16383
        int j  = idx & 7;
        int l  = (idx >> 3) & 63;
        int mt = (idx >> 9) & 3;
        int ki = (idx >> 11) & 7;
        int r  = mt * 16 + (l & 15);
        int c  = ki * 32 + (l >> 4) * 8 + j;
        float scale = gamma[r] * rsqrtf(var[r] + 1e-5f);
        w1a[idx] = f2bf(w1[r * CC + c] * scale);
        if (idx < CR) {
            float s = gamma[idx] * rsqrtf(var[idx] + 1e-5f);
            b1f[idx] = (b1[idx] - mean[idx]) * s + beta[idx];
        }
    }
}

// ---------------------------------------------------------------------------
// conv1 (MFMA): y[px][r] = ReLU6(x[px][c] . w1a[r][c] + b1f[r]) -> bf16
// ybf[b][h][px][r]. Grid (H,B)=512 blocks, 4 waves; wave wv owns px tile
// wv*16..+16 (n = px), all 64 r (4 m-tiles). B-frag (x) via per-lane global
// loads (4 fully-used 64B segments per instr; each x byte read once/block).
// ---------------------------------------------------------------------------
__global__ __launch_bounds__(256) void conv1_kernel(
    const float* __restrict__ x, const unsigned short* __restrict__ w1a,
    const float* __restrict__ b1f, unsigned short* __restrict__ ybf)
{
    const int tid  = threadIdx.x;
    const int h    = blockIdx.x;
    const int b    = blockIdx.y;
    const int lane = tid & 63;
    const int wv   = tid >> 6;
    const int l15  = lane & 15;
    const int q    = lane >> 4;
    const int px   = wv * 16 + l15;

    const float*  xc   = x + (size_t)b * CC * HW + h * WW + px;  // + c*HW
    const short8* w1a8 = (const short8*)w1a;

    f32x4 cfr[4];
    #pragma unroll
    for (int mt = 0; mt < 4; ++mt) cfr[mt] = (f32x4){0.f, 0.f, 0.f, 0.f};

    #pragma unroll
    for (int ki = 0; ki < 8; ++ki) {
        short8 bfr;
        #pragma unroll
        for (int j = 0; j < 8; ++j) {
            float v = xc[(ki * 32 + q * 8 + j) * HW];
            bfr[j] = (short)f2bf(v);
        }
        #pragma unroll
        for (int mt = 0; mt < 4; ++mt) {
            short8 afr = w1a8[(ki * 4 + mt) * 64 + lane];
            cfr[mt] = __builtin_amdgcn_mfma_f32_16x16x32_bf16(afr, bfr, cfr[mt], 0, 0, 0);
        }
    }

    // Epilogue: bias + ReLU6, pack 4 bf16 (rows q*4..q*4+3) -> one 8B store.
    unsigned short* yb = ybf + ((size_t)(b * HH + h) * WW + px) * CR;
    #pragma unroll
    for (int mt = 0; mt < 4; ++mt) {
        unsigned pk[2];
        #pragma unroll
        for (int rp = 0; rp < 2; ++rp) {
            float v0 = cfr[mt][rp * 2 + 0] + b1f[mt * 16 + q * 4 + rp * 2 + 0];
            float v1 = cfr[mt][rp * 2 + 1] + b1f[mt * 16 + q * 4 + rp * 2 + 1];
            v0 = fminf(fmaxf(v0, 0.0f), 6.0f);
            v1 = fminf(fmaxf(v1, 0.0f), 6.0f);
            pk[rp] = (unsigned)f2bf(v0) | ((unsigned)f2bf(v1) << 16);
        }
        *(uint2*)(yb + mt * 16 + q * 4) = make_uint2(pk[0], pk[1]);
    }
}

// ---------------------------------------------------------------------------
// invol: per-pixel kernels via MFMA + involution accumulate.
// Taps via 1 coalesced load + 4 __shfl per (channel, di): lane l loads
// x[ch][hh][l]; neighbors x[l+/-1], x[l+/-2] come from bpermute. Out-of-range
// columns masked through val[dj] (kern zeroed), so shuffle wrap is harmless.
// Cuts tap VMEM instrs and L1 traffic 5x vs the 5-offset-load scheme.
// ---------------------------------------------------------------------------
__global__ __launch_bounds__(256, 4) void invol_kernel(
    const float* __restrict__ x, const unsigned short* __restrict__ ybf,
    const unsigned short* __restrict__ w2p, const float* __restrict__ b2,
    float* __restrict__ out)
{
    __shared__ float klds[4][32 * 65];    // per-wave kern tiles, 33,280 B

    const int tid  = threadIdx.x;
    const int h    = blockIdx.x;
    const int b    = blockIdx.y;
    const int gq   = blockIdx.z;          // 0..1
    const int lane = tid & 63;
    const int wv   = __builtin_amdgcn_readfirstlane(tid >> 6);
    float* kw = klds[wv];

    const int l15 = lane & 15;
    const int q   = lane >> 4;

    // A fragments: y[px = mt*16+l15][k = ki*32 + q*8 + j]
    short8 afr[4][2];
    const unsigned short* yb = ybf + (size_t)(b * HH + h) * WW * CR;
    #pragma unroll
    for (int mt = 0; mt < 4; ++mt)
        #pragma unroll
        for (int ki = 0; ki < 2; ++ki)
            afr[mt][ki] = *(const short8*)(yb + (mt * 16 + l15) * CR + ki * 32 + q * 8);

    // tap-column validity (dj: column lane+dj-2 must be in [0, W))
    bool val[5];
    #pragma unroll
    for (int dj = 0; dj < 5; ++dj) {
        int ww  = lane + dj - 2;
        val[dj] = (ww >= 0) && (ww < WW);
    }

    const short8* w2p8 = (const short8*)w2p;

    #pragma unroll 1
    for (int gl = 0; gl < 4; ++gl) {
        const int g = gq * 16 + wv * 4 + gl;   // uniform

        // C init = b2 broadcast (col n = nt*16 + l15)
        f32x4 cfr[4][2];
        #pragma unroll
        for (int nt = 0; nt < 2; ++nt) {
            int nl = nt * 16 + l15;
            float vb = b2[g * KK + min(nl, KK - 1)];
            vb = (nl < KK) ? vb : 0.0f;
            #pragma unroll
            for (int mt = 0; mt < 4; ++mt)
                cfr[mt][nt] = (f32x4){vb, vb, vb, vb};
        }

        // MFMA: kern[px][n] = sum_k y[px][k] * w2[n][k] + b2
        #pragma unroll
        for (int nt = 0; nt < 2; ++nt) {
            short8 bf0 = w2p8[((g * 2 + nt) * 2 + 0) * 64 + lane];
            short8 bf1 = w2p8[((g * 2 + nt) * 2 + 1) * 64 + lane];
            #pragma unroll
            for (int mt = 0; mt < 4; ++mt) {
                cfr[mt][nt] = __builtin_amdgcn_mfma_f32_16x16x32_bf16(
                    afr[mt][0], bf0, cfr[mt][nt], 0, 0, 0);
                cfr[mt][nt] = __builtin_amdgcn_mfma_f32_16x16x32_bf16(
                    afr[mt][1], bf1, cfr[mt][nt], 0, 0, 0);
            }
        }

        // C -> LDS: kern_lds[n][px], row stride 65
        #pragma unroll
        for (int mt = 0; mt < 4; ++mt)
            #pragma unroll
            for (int nt = 0; nt < 2; ++nt) {
                int n  = nt * 16 + l15;
                int px = mt * 16 + q * 4;
                #pragma unroll
                for (int r = 0; r < 4; ++r)
                    kw[n * 65 + px + r] = cfr[mt][nt][r];
            }

        // involution: 1 load + 4 shuffles per (ch, di)
        float oacc[GC];
        #pragma unroll
        for (int j = 0; j < GC; ++j) oacc[j] = 0.0f;

        const float* xg = x + (size_t)(b * CC + g * GC) * HW;
        #pragma unroll
        for (int di = 0; di < 5; ++di) {
            int hh = h + di - 2;                 // uniform
            if (hh >= 0 && hh < HH) {
                float ks[5];
                #pragma unroll
                for (int dj = 0; dj < 5; ++dj) {
                    float kv = kw[(di * 5 + dj) * 65 + lane];   // 2-way, free
                    ks[dj] = val[dj] ? kv : 0.0f;
                }
                #pragma unroll
                for (int j = 0; j < GC; ++j) {
                    float xv  = xg[(j * HH + hh) * WW + lane];  // coalesced
                    float xm2 = __shfl(xv, lane - 2, 64);
                    float xm1 = __shfl(xv, lane - 1, 64);
                    float xp1 = __shfl(xv, lane + 1, 64);
                    float xp2 = __shfl(xv, lane + 2, 64);
                    oacc[j] = fmaf(ks[0], xm2, oacc[j]);
                    oacc[j] = fmaf(ks[1], xm1, oacc[j]);
                    oacc[j] = fmaf(ks[2], xv,  oacc[j]);
                    oacc[j] = fmaf(ks[3], xp1, oacc[j]);
                    oacc[j] = fmaf(ks[4], xp2, oacc[j]);
                }
            }
        }

        float* oc = out + ((size_t)(b * CC + g * GC) * HH + h) * WW + lane;
        #pragma unroll
        for (int j = 0; j < GC; ++j) oc[j * HW] = oacc[j];
    }
}

extern "C" void kernel_launch(void* const* d_in, const int* in_sizes, int n_in,
                              void* d_out, int out_size, void* d_ws, size_t ws_size,
                              hipStream_t stream) {
    const float* x     = (const float*)d_in[0];
    const float* w1    = (const float*)d_in[1];
    const float* b1    = (const float*)d_in[2];
    const float* gamma = (const float*)d_in[3];
    const float* beta  = (const float*)d_in[4];
    const float* mean  = (const float*)d_in[5];
    const float* var   = (const float*)d_in[6];
    const float* w2    = (const float*)d_in[7];
    const float* b2    = (const float*)d_in[8];
    float* out = (float*)d_out;

    char* ws = (char*)d_ws;
    unsigned short* w1a = (unsigned short*)ws;                    // 16384 bf16 = 32 KB
    float*          b1f = (float*)(ws + 32768);                   // 64 f = 256 B
    unsigned short* w2p = (unsigned short*)(ws + 33024);          // 65536 bf16 = 128 KB
    unsigned short* ybf = (unsigned short*)(ws + 164096);         // 2,097,152 bf16 = 4 MB

    prep_kernel<<<320, 256, 0, stream>>>(w1, b1, gamma, beta, mean, var, w2,
                                         w1a, b1f, w2p);
    conv1_kernel<<<dim3(HH, BB), 256, 0, stream>>>(x, w1a, b1f, ybf);
    invol_kernel<<<dim3(HH, BB, 2), 256, 0, stream>>>(x, ybf, w2p, b2, out);
}